// Round 1
// baseline (235.382 us; speedup 1.0000x reference)
//
#include <hip/hip_runtime.h>
#include <math.h>

// Problem constants (B=2,S=2048,D=1024, N_EXP=8, TOP_K=2, CAP_FACTOR=1.25)
#define NTOK   4096          // B*S
#define DIM    1024
#define NEXP   8
#define CAP    1280          // int(4096*2*1.25/8)
#define NSLOT  (NTOK*2)      // 8192

// d_out layout: gates[4096][2] | exp_mask[4096][8][1280] | exp_batches[8][1280][1024]
#define OUT_MASK_OFF   ((size_t)NTOK*2)                       // 8192
#define OUT_BATCH_OFF  (OUT_MASK_OFF + (size_t)NTOK*NEXP*CAP) // 8192 + 41943040

// ---------------- Kernel 1: gating (logits -> top2 -> softmax) ----------------
__global__ __launch_bounds__(256) void gate_kernel(
    const float* __restrict__ x, const float* __restrict__ Wg,
    float* __restrict__ gates_out,
    int* __restrict__ e0a, int* __restrict__ e1a,
    float* __restrict__ g0a, float* __restrict__ g1a)
{
    const int t   = blockIdx.x;
    const int tid = threadIdx.x;

    // Each of 256 threads handles 4 contiguous elements (float4) of the D=1024 dot.
    const float4 xv = ((const float4*)(x + (size_t)t * DIM))[tid];

    float acc[NEXP];
#pragma unroll
    for (int e = 0; e < NEXP; ++e) {
        const float4 w = ((const float4*)(Wg + (size_t)e * DIM))[tid];
        acc[e] = xv.x * w.x + xv.y * w.y + xv.z * w.z + xv.w * w.w;
    }

    // wave (64-lane) butterfly reduce
#pragma unroll
    for (int off = 32; off >= 1; off >>= 1) {
#pragma unroll
        for (int e = 0; e < NEXP; ++e)
            acc[e] += __shfl_xor(acc[e], off);
    }

    __shared__ float red[4][NEXP];
    __shared__ float logits[NEXP];
    const int wave = tid >> 6;
    if ((tid & 63) == 0) {
#pragma unroll
        for (int e = 0; e < NEXP; ++e) red[wave][e] = acc[e];
    }
    __syncthreads();
    if (tid < NEXP) {
        logits[tid] = red[0][tid] + red[1][tid] + red[2][tid] + red[3][tid];
    }
    __syncthreads();

    if (tid == 0) {
        // top-2, lower index wins ties (matches lax.top_k)
        float best = -INFINITY, second = -INFINITY;
        int b0 = 0, b1 = 0;
#pragma unroll
        for (int e = 0; e < NEXP; ++e) {
            const float v = logits[e];
            if (v > best)        { second = best; b1 = b0; best = v; b0 = e; }
            else if (v > second) { second = v; b1 = e; }
        }
        // softmax over [best, second] (best >= second)
        const float e1v = __expf(second - best);
        const float inv = 1.0f / (1.0f + e1v);
        const float g0 = inv, g1 = e1v * inv;

        gates_out[(size_t)t * 2]     = g0;
        gates_out[(size_t)t * 2 + 1] = g1;
        e0a[t] = b0; e1a[t] = b1;
        g0a[t] = g0; g1a[t] = g1;
    }
}

// ---------------- Kernel 2: deterministic serial-order position scan ----------------
__global__ __launch_bounds__(256) void scan_kernel(
    const int* __restrict__ e0a, const int* __restrict__ e1a,
    int* __restrict__ pos0a, int* __restrict__ pos1a,
    int* __restrict__ inv_out)
{
    __shared__ int cnt[256][NEXP + 1];   // +1 pad to break bank conflicts
    __shared__ int invs[NEXP * CAP];     // 10240 ints

    const int tid = threadIdx.x;

    for (int i = tid; i < NEXP * CAP; i += 256) invs[i] = -1;

    // Thread tid owns slots [tid*32, tid*32+32) == tokens [tid*16, tid*16+16)
    const int tok0 = tid * 16;
    int ex[32];
    int local[NEXP];
#pragma unroll
    for (int e = 0; e < NEXP; ++e) local[e] = 0;
#pragma unroll
    for (int j = 0; j < 16; ++j) {
        const int a = e0a[tok0 + j];
        const int b = e1a[tok0 + j];
        ex[2 * j]     = a;
        ex[2 * j + 1] = b;
        local[a]++; local[b]++;
    }

    int val[NEXP];
#pragma unroll
    for (int e = 0; e < NEXP; ++e) { val[e] = local[e]; cnt[tid][e] = val[e]; }

    // Hillis-Steele inclusive scan over 256 threads (8 lanes each)
    for (int off = 1; off < 256; off <<= 1) {
        __syncthreads();
        int nb[NEXP];
        const bool has = (tid >= off);
        if (has) {
#pragma unroll
            for (int e = 0; e < NEXP; ++e) nb[e] = cnt[tid - off][e];
        }
        __syncthreads();
        if (has) {
#pragma unroll
            for (int e = 0; e < NEXP; ++e) val[e] += nb[e];
        }
#pragma unroll
        for (int e = 0; e < NEXP; ++e) cnt[tid][e] = val[e];
    }
    __syncthreads();

    int run[NEXP];
#pragma unroll
    for (int e = 0; e < NEXP; ++e) run[e] = val[e] - local[e];  // exclusive prefix

#pragma unroll
    for (int j = 0; j < 32; ++j) {
        const int e = ex[j];
        const int p = run[e]++;
        const int tok = tok0 + (j >> 1);
        if (j & 1) pos1a[tok] = p; else pos0a[tok] = p;
        if (p < CAP) invs[e * CAP + p] = tok;
    }
    __syncthreads();

    for (int i = tid; i < NEXP * CAP; i += 256) inv_out[i] = invs[i];
}

// ---------------- Kernel 3: exp_mask writer (one token row [8][1280] per block) ----------------
__global__ __launch_bounds__(256) void mask_kernel(
    const int* __restrict__ e0a, const int* __restrict__ e1a,
    const int* __restrict__ pos0a, const int* __restrict__ pos1a,
    const float* __restrict__ g0a, const float* __restrict__ g1a,
    float* __restrict__ mask_out)
{
    const int t   = blockIdx.x;
    const int tid = threadIdx.x;

    const int   e0 = e0a[t], e1 = e1a[t];
    const int   p0 = pos0a[t], p1 = pos1a[t];
    const float g0 = g0a[t],  g1 = g1a[t];

    float4* dst = (float4*)(mask_out + (size_t)t * NEXP * CAP);

#pragma unroll
    for (int i = 0; i < 10; ++i) {
        const int idx = tid + i * 256;       // 0..2559, float4 index in the row
        const int e   = idx / (CAP / 4);     // /320
        const int c   = (idx - e * (CAP / 4)) * 4;

        float4 v = make_float4(0.f, 0.f, 0.f, 0.f);
        // p >= CAP (dropped) can never match since c+3 <= 1279
        if (e == e0) {
            if (p0 == c)     v.x = g0;
            if (p0 == c + 1) v.y = g0;
            if (p0 == c + 2) v.z = g0;
            if (p0 == c + 3) v.w = g0;
        }
        if (e == e1) {
            if (p1 == c)     v.x = g1;
            if (p1 == c + 1) v.y = g1;
            if (p1 == c + 2) v.z = g1;
            if (p1 == c + 3) v.w = g1;
        }
        dst[idx] = v;
    }
}

// ---------------- Kernel 4: exp_batches writer (one (e,cap) row per block) ----------------
__global__ __launch_bounds__(256) void batch_kernel(
    const int* __restrict__ inv, const float* __restrict__ x,
    float* __restrict__ batch_out)
{
    const int row = blockIdx.x;            // 0..10239  (= e*1280 + c)
    const int tid = threadIdx.x;
    const int tok = inv[row];

    float4 v = make_float4(0.f, 0.f, 0.f, 0.f);
    if (tok >= 0)
        v = ((const float4*)(x + (size_t)tok * DIM))[tid];

    ((float4*)(batch_out + (size_t)row * DIM))[tid] = v;
}

extern "C" void kernel_launch(void* const* d_in, const int* in_sizes, int n_in,
                              void* d_out, int out_size, void* d_ws, size_t ws_size,
                              hipStream_t stream)
{
    const float* x  = (const float*)d_in[0];
    const float* Wg = (const float*)d_in[1];

    float* out   = (float*)d_out;
    float* gates = out;
    float* mask  = out + OUT_MASK_OFF;
    float* batch = out + OUT_BATCH_OFF;

    int* wsi = (int*)d_ws;
    int*   e0a  = wsi;
    int*   e1a  = wsi + NTOK;
    float* g0a  = (float*)(wsi + 2 * NTOK);
    float* g1a  = (float*)(wsi + 3 * NTOK);
    int*   p0a  = wsi + 4 * NTOK;
    int*   p1a  = wsi + 5 * NTOK;
    int*   inv  = wsi + 6 * NTOK;          // NEXP*CAP ints

    gate_kernel <<<NTOK, 256, 0, stream>>>(x, Wg, gates, e0a, e1a, g0a, g1a);
    scan_kernel <<<1, 256, 0, stream>>>(e0a, e1a, p0a, p1a, inv);
    mask_kernel <<<NTOK, 256, 0, stream>>>(e0a, e1a, p0a, p1a, g0a, g1a, mask);
    batch_kernel<<<NEXP * CAP, 256, 0, stream>>>(inv, x, batch);
}